// Round 16
// baseline (1182.094 us; speedup 1.0000x reference)
//
#include <hip/hip_runtime.h>
#include <hip/hip_bf16.h>
#include <math.h>

// Problem constants (fixed by the reference)
#define Nn 50000
#define Ee 400000
#define Gg 2000
#define NPGc 25
#define Hc 128
#define Lc 5
// branch row padding: 128-aligned so every GEMM tile is branch-homogeneous
#define M2c 50048              // = 64 * 782 = 128 * 391
#define R2c 100096             // = 2 * M2c

typedef __attribute__((ext_vector_type(8))) short short8;   // 8 bf16 = 4 VGPRs
typedef __attribute__((ext_vector_type(4))) float fx4;      // MFMA accumulator

__device__ inline short bf16r(float x){
  unsigned u = __float_as_uint(x);
  unsigned r = (u + 0x7fffu + ((u >> 16) & 1u)) >> 16;
  return (short)r;
}
__device__ inline float bf16f(short s){
  return __uint_as_float(((unsigned)(unsigned short)s) << 16);
}

// ------------------------------------------------------------------
// Graph preprocessing
// ------------------------------------------------------------------
__global__ void deg_kernel(const int* __restrict__ dst, int* __restrict__ deg, int E){
  int i = blockIdx.x * blockDim.x + threadIdx.x;
  if (i < E) atomicAdd(&deg[dst[i]], 1);
}

__global__ void scan1_kernel(const int* __restrict__ deg, int* __restrict__ part,
                             int* __restrict__ bsums, int n){
  __shared__ int tmp[1024];
  int b = blockIdx.x, t = threadIdx.x;
  int i = b * 1024 + t;
  int v = (i < n) ? deg[i] : 0;
  tmp[t] = v;
  __syncthreads();
  for (int off = 1; off < 1024; off <<= 1){
    int add = (t >= off) ? tmp[t - off] : 0;
    __syncthreads();
    tmp[t] += add;
    __syncthreads();
  }
  part[i] = tmp[t];
  if (t == 1023) bsums[b] = tmp[1023];
}
__global__ void scan2_kernel(int* __restrict__ bsums, int nb){
  if (threadIdx.x == 0){
    int s = 0;
    for (int i = 0; i < nb; i++){ s += bsums[i]; bsums[i] = s; }
  }
}
__global__ void scan3_kernel(const int* __restrict__ part, const int* __restrict__ bsums,
                             int* __restrict__ rowstart, int n){
  int i = blockIdx.x * blockDim.x + threadIdx.x;
  if (i == 0) rowstart[0] = 0;
  if (i < n){
    int b = i >> 10;
    int base = b ? bsums[b - 1] : 0;
    rowstart[i + 1] = part[i] + base;
  }
}

__global__ void copy_int_kernel(const int* __restrict__ a, int* __restrict__ b, int n){
  int i = blockIdx.x * blockDim.x + threadIdx.x;
  if (i < n) b[i] = a[i];
}

// packed edge record: (code << 16) | (src % NPGc)  -- src and dst are
// ALWAYS in the same graph (reference construction), so the graph-local
// src index (0..24) is sufficient.
__global__ void scatter_kernel(const int* __restrict__ src, const int* __restrict__ dst,
                               const int* __restrict__ ef, int* cursor,
                               int* __restrict__ pk_srt, int E){
  int i = blockIdx.x * blockDim.x + threadIdx.x;
  if (i >= E) return;
  int p = atomicAdd(&cursor[dst[i]], 1);
  int code = ef[i * 3 + 0] * 25 + ef[i * 3 + 1] * 5 + ef[i * 3 + 2];
  pk_srt[p] = (code << 16) | (src[i] % NPGc);
}

// amp/att sized M2c (branch-local rows; both branches share the graph)
__global__ void ampatt_kernel(const int* __restrict__ deg, float* __restrict__ amp,
                              float* __restrict__ att, int n){
  int i = blockIdx.x * blockDim.x + threadIdx.x;
  if (i >= n) return;
  if (i >= Nn){ amp[i] = 0.f; att[i] = 0.f; return; }
  float d = (float)deg[i];
  float ld = logf(d + 1.0f);
  amp[i] = ld;
  att[i] = (deg[i] > 0) ? (1.0f / ld) : 0.0f;
}

// ------------------------------------------------------------------
// Node embedding, BOTH branches stacked
// ------------------------------------------------------------------
__global__ void embed2_kernel(const int* __restrict__ nf,
                              const float* __restrict__ aemb_f,
                              const float* __restrict__ aemb_t,
                              float* __restrict__ h, short* __restrict__ h16){
  int idx = blockIdx.x * blockDim.x + threadIdx.x;
  if (idx >= R2c * Hc) return;
  int n = idx >> 7, c = idx & 127;
  int br = n >= M2c;
  int local = n - br * M2c;
  if (local >= Nn){ h[idx] = 0.f; h16[idx] = 0; return; }
  const float* aemb = br ? aemb_t : aemb_f;
  float s = 0.f;
#pragma unroll
  for (int f = 0; f < 9; f++){
    int row = nf[local * 9 + f] + 16 * f;
    s += aemb[row * Hc + c];
  }
  h[idx] = s;
  h16[idx] = bf16r(s);
}

// bsum2[b][code][c]: 125 distinct edge embeddings, both branches
__global__ void bsum2_kernel(const float* __restrict__ bemb_f, const float* __restrict__ bemb_t,
                             float* __restrict__ bsum2){
  int idx = blockIdx.x * blockDim.x + threadIdx.x;
  if (idx >= 2 * 125 * Hc) return;
  int b = idx / (125 * Hc);
  int rem = idx % (125 * Hc);
  int code = rem >> 7, c = rem & 127;
  int e0 = code / 25, e1 = (code / 5) % 5, e2 = code % 5;
  const float* bemb = b ? bemb_t : bemb_f;
  bsum2[idx] = bemb[e0 * Hc + c] + bemb[(5 + e1) * Hc + c] + bemb[(10 + e2) * Hc + c];
}

// ------------------------------------------------------------------
// up-front weight converts, both branches x 5 layers
// ------------------------------------------------------------------
__global__ void conv_pre_all_kernel(const float* __restrict__ wpre_f,
                                    const float* __restrict__ wpre_t,
                                    short* __restrict__ btpre_all){
  int idx = blockIdx.x * blockDim.x + threadIdx.x;
  if (idx >= 2 * Lc * 256 * 128) return;
  int bl = idx / (256 * 128);
  int rem = idx % (256 * 128);
  int col = rem >> 7, k = rem & 127;
  int b = bl / Lc, l = bl % Lc;
  const float* wl = (b ? wpre_t : wpre_f) + (size_t)l * 384 * 128;
  float v = (col < 128) ? wl[k * 128 + col] : wl[(128 + k) * 128 + (col - 128)];
  btpre_all[(size_t)bl * 256 * 128 + col * 128 + k] = bf16r(v);
}
__global__ void conv_post_all_kernel(const float* __restrict__ wpost_f,
                                     const float* __restrict__ wpost_t,
                                     short* __restrict__ btpost_all){
  int idx = blockIdx.x * blockDim.x + threadIdx.x;
  if (idx >= 2 * Lc * 1664 * 128) return;
  int bl = idx / (1664 * 128);
  int rem = idx % (1664 * 128);
  int k = rem >> 7, c = rem & 127;
  int b = bl / Lc, l = bl % Lc;
  const float* wl = (b ? wpost_t : wpost_f) + (size_t)l * 1664 * 128;
  btpost_all[(size_t)bl * 128 * 1664 + (size_t)c * 1664 + k] = bf16r(wl[(size_t)k * 128 + c]);
}

// ezt16_all[bl][code][c] (bf16) = bsum2[b][code][:] @ W_e[b,l] + b_pre[b,l]
__global__ void ezt_all_kernel(const float* __restrict__ wpre_f, const float* __restrict__ wpre_t,
                               const float* __restrict__ bpre_f, const float* __restrict__ bpre_t,
                               const float* __restrict__ bsum2, short* __restrict__ ezt16_all){
  int code = blockIdx.x;
  int bl   = blockIdx.y;
  int t = threadIdx.x;
  int b = bl / Lc, l = bl % Lc;
  const float* wl = (b ? wpre_t : wpre_f) + (size_t)l * 384 * 128 + 256 * 128;
  const float* bp = (b ? bpre_t : bpre_f) + (size_t)l * 128;
  __shared__ float bs[128];
  bs[t] = bsum2[((size_t)b * 125 + code) * 128 + t];
  __syncthreads();
  float acc = bp[t];
#pragma unroll 8
  for (int k = 0; k < 128; k++) acc += bs[k] * wl[k * 128 + t];
  ezt16_all[((size_t)bl * 125 + code) * 128 + t] = bf16r(acc);
}

// ------------------------------------------------------------------
// Graph readout (merged): block b*Gg+g -> branch b, graph g
// ------------------------------------------------------------------
__global__ void readout2_kernel(const float* __restrict__ h,
                                float* __restrict__ r3, float* __restrict__ r2){
  int bi = blockIdx.x;
  int br = bi >= Gg;
  int g = bi - br * Gg;
  int c = threadIdx.x;
  float mn = 3.402823466e38f, mx = -3.402823466e38f, s = 0.f;
  const float* hp = h + ((size_t)br * M2c + (size_t)g * NPGc) * Hc + c;
#pragma unroll
  for (int i = 0; i < NPGc; i++){
    float v = hp[i * Hc];
    mn = fminf(mn, v); mx = fmaxf(mx, v); s += v;
  }
  float* r = br ? r2 : r3;
  r[(size_t)g * 384 + c]       = mn;
  r[(size_t)g * 384 + 128 + c] = mx;
  r[(size_t)g * 384 + 256 + c] = s * (1.0f / NPGc);
}

// ------------------------------------------------------------------
// Fused head, one graph per block
// ------------------------------------------------------------------
__global__ __launch_bounds__(256)
void head_kernel(const float* __restrict__ r2, const float* __restrict__ r3,
                 const float* __restrict__ w_out3, const float* __restrict__ b_out3,
                 const float* __restrict__ w1, const float* __restrict__ b1,
                 const float* __restrict__ w2, const float* __restrict__ b2,
                 float* __restrict__ out)
{
  __shared__ float r3_s[384];
  __shared__ float x_s[640];
  __shared__ float h1_s[128];
  __shared__ float partial[256];
  int g = blockIdx.x, t = threadIdx.x;

  for (int i = t; i < 384; i += 256){
    float v2 = r2[(size_t)g * 384 + i];
    r3_s[i] = r3[(size_t)g * 384 + i];
    x_s[i] = v2;
  }
  __syncthreads();

  {
    float acc = b_out3[t];
#pragma unroll 8
    for (int k = 0; k < 384; k++) acc += r3_s[k] * w_out3[k * 256 + t];
    x_s[384 + t] = acc;
  }
  __syncthreads();

  {
    int c = t & 127, half = t >> 7;
    float acc = half ? 0.f : b1[c];
    int kb = half * 320;
#pragma unroll 8
    for (int k = kb; k < kb + 320; k++) acc += x_s[k] * w1[k * 128 + c];
    partial[t] = acc;
  }
  __syncthreads();
  if (t < 128) h1_s[t] = fmaxf(partial[t] + partial[t + 128], 0.f);
  __syncthreads();

  {
    int c = t & 127, half = t >> 7;
    float acc = half ? 0.f : b2[c];
    int kb = half * 64;
#pragma unroll 8
    for (int k = kb; k < kb + 64; k++) acc += h1_s[k] * w2[k * 128 + c];
    partial[t] = acc;
  }
  __syncthreads();
  if (t < 128) out[(size_t)g * 128 + t] = partial[t] + partial[t + 128];
}

// ------------------------------------------------------------------
// fgemm_agg v6: v5 body (hd-factoring) at 6 blocks/CU -- LDS 26,624 B
// fits exactly 6x (159,744 <= 163,840); VGPR 40 << cap 85. Occupancy
// probe: if phase C is latency-gated, +20% resident waves pays.
// ------------------------------------------------------------------
__global__ __launch_bounds__(256, 6)
void fgemm_agg_kernel(const short* __restrict__ h16,     // [R2c][128]
                      const short* __restrict__ pre0, const short* __restrict__ pre1,
                      const int* __restrict__ ez0, const int* __restrict__ ez1,
                      const int* __restrict__ pk_srt, const int* __restrict__ rowstart,
                      short* __restrict__ aggG)          // [R2c][512]
{
  __shared__ short h_s[32 * 128];     // 8 KB (rows 25..31 unstaged garbage)
  __shared__ short hsd_s[32 * 256];   // 16 KB
  __shared__ int pk_s[512];           // 2 KB graph edge list

  int tid = threadIdx.x;
  int bi = blockIdx.x;
  int brn = bi >= Gg;
  int g = bi - brn * Gg;
  const short* h16b = h16 + (size_t)brn * M2c * 128;
  const short* Bt = brn ? pre1 : pre0;
  const int* ez16 = brn ? ez1 : ez0;
  short* aggOut = aggG + (size_t)brn * M2c * 512;
  int base = g * NPGc;

  // ---- Phase A: stage h (swizzled) + the graph's edge list ----
  int e_lo = rowstart[base];
  {
    int ecnt = rowstart[base + NPGc] - e_lo;
    if (ecnt > 512) ecnt = 512;
    for (int t = tid; t < ecnt; t += 256) pk_s[t] = pk_srt[e_lo + t];

    const int* src = (const int*)(h16b + (size_t)base * 128);
    int* dst = (int*)h_s;
    for (int t = tid; t < NPGc * 64; t += 256){
      int row = t >> 6, ci = t & 63;
      dst[row * 64 + (ci ^ ((row & 7) << 2))] = src[t];
    }
  }
  __syncthreads();

  // ---- Phase B: MFMA GEMM 32x256 = 32x128 @ 128x256 ----
  int wv = tid >> 6, ln = tid & 63;
  int l15 = ln & 15, lq = ln >> 4;
  {
    fx4 acc[2][4];
#pragma unroll
    for (int mt = 0; mt < 2; mt++)
#pragma unroll
      for (int ct = 0; ct < 4; ct++) acc[mt][ct] = (fx4){0.f, 0.f, 0.f, 0.f};

    // A fragments from LDS: lane l -> row = mt*16 + (l&15), k = ks*32 + (l>>4)*8
    short8 af[2][4];
#pragma unroll
    for (int mt = 0; mt < 2; mt++){
      int row = mt * 16 + l15;
#pragma unroll
      for (int ks = 0; ks < 4; ks++){
        int sk = ks * 32 + lq * 8;
        af[mt][ks] = *(const short8*)(h_s + row * 128 + (sk ^ ((row & 7) << 3)));
      }
    }
    // B fragments from global: col = wv*64 + ct*16 + (l&15), same k mapping
#pragma unroll
    for (int ks = 0; ks < 4; ks++){
#pragma unroll
      for (int ct = 0; ct < 4; ct++){
        int col = wv * 64 + ct * 16 + l15;
        short8 bf = *(const short8*)(Bt + (size_t)col * 128 + ks * 32 + lq * 8);
        acc[0][ct] = __builtin_amdgcn_mfma_f32_16x16x32_bf16(af[0][ks], bf, acc[0][ct], 0, 0, 0);
        acc[1][ct] = __builtin_amdgcn_mfma_f32_16x16x32_bf16(af[1][ks], bf, acc[1][ct], 0, 0, 0);
      }
    }
    // write hsd to LDS (C/D: col = lane&15, row = (lane>>4)*4 + r)
#pragma unroll
    for (int mt = 0; mt < 2; mt++){
#pragma unroll
      for (int ct = 0; ct < 4; ct++){
        int cc = wv * 64 + ct * 16 + l15;
#pragma unroll
        for (int r = 0; r < 4; r++){
          int row = mt * 16 + lq * 4 + r;
          hsd_s[row * 256 + (cc ^ ((row & 7) << 3))] = bf16r(acc[mt][ct][r]);
        }
      }
    }
  }
  __syncthreads();

  // ---- Phase C: aggregation (pk + hs from LDS; hd factored out) ----
  int sub = tid & 15;
  int go = sub * 4;
  const int* hsd_i = (const int*)hsd_s;

#pragma unroll
  for (int rnd = 0; rnd < 2; rnd++){
    int nd = rnd * 16 + (tid >> 4);
    if (nd >= NPGc) continue;
    int node = base + nd;
    int e0 = rowstart[node], e1 = rowstart[node + 1];
    short* o = aggOut + (size_t)node * 512 + sub * 8;
    if (e1 <= e0){
      short8 z = {0, 0, 0, 0, 0, 0, 0, 0};
      *(short8*)(o)       = z;
      *(short8*)(o + 128) = z;
      *(short8*)(o + 256) = z;
      *(short8*)(o + 384) = z;
      continue;
    }

    // dst-half of pretrans (LDS, swizzled): ints 64+go of row nd
    float hdv[8];
    {
      int4 hd = *(const int4*)(hsd_i + nd * 128 + ((64 + go) ^ ((nd & 7) << 2)));
      const int* hp = (const int*)&hd;
#pragma unroll
      for (int i = 0; i < 4; i++){
        hdv[2 * i]     = __uint_as_float(((unsigned)hp[i]) << 16);
        hdv[2 * i + 1] = __uint_as_float(((unsigned)hp[i]) & 0xffff0000u);
      }
    }

    float sum[8], sq[8], mx[8], mn[8];
#pragma unroll
    for (int j = 0; j < 8; j++){
      sum[j] = 0.f; sq[j] = 0.f;
      mx[j] = -3.402823466e38f; mn[j] = 3.402823466e38f;
    }

    for (int k = e0; k < e1; k += 4){
      int pk[4];
#pragma unroll
      for (int t2 = 0; t2 < 4; t2++){
        int kk = (k + t2 < e1) ? (k + t2) : (e1 - 1);
        int rel = kk - e_lo;
        pk[t2] = (rel < 512) ? pk_s[rel] : pk_srt[kk];
      }
      int4 ev[4], hv[4];
#pragma unroll
      for (int t2 = 0; t2 < 4; t2++){
        int s = pk[t2] & 0xffff;
        ev[t2] = *(const int4*)(ez16 + (pk[t2] >> 16) * 64 + go);
        hv[t2] = *(const int4*)(hsd_i + s * 128 + (go ^ ((s & 7) << 2)));
      }
#pragma unroll
      for (int t2 = 0; t2 < 4; t2++){
        if (k + t2 < e1){
          const int* pp = (const int*)&hv[t2];
          const int* ee = (const int*)&ev[t2];
#pragma unroll
          for (int i = 0; i < 4; i++){
            float y0 = __uint_as_float(((unsigned)pp[i]) << 16)
                     + __uint_as_float(((unsigned)ee[i]) << 16);
            float y1 = __uint_as_float(((unsigned)pp[i]) & 0xffff0000u)
                     + __uint_as_float(((unsigned)ee[i]) & 0xffff0000u);
            sum[2 * i] += y0;     sq[2 * i] += y0 * y0;
            mx[2 * i] = fmaxf(mx[2 * i], y0); mn[2 * i] = fminf(mn[2 * i], y0);
            sum[2 * i + 1] += y1; sq[2 * i + 1] += y1 * y1;
            mx[2 * i + 1] = fmaxf(mx[2 * i + 1], y1); mn[2 * i + 1] = fminf(mn[2 * i + 1], y1);
          }
        }
      }
    }

    float d = (float)(e1 - e0);
    float rd = 1.0f / d;
    short8 sm, sx, sn, sd;
#pragma unroll
    for (int j = 0; j < 8; j++){
      float my = sum[j] * rd;
      float v = sq[j] * rd - my * my; v = v > 0.f ? v : 0.f;  // var shift-invariant
      sm[j] = bf16r(my + hdv[j]);
      sx[j] = bf16r(mx[j] + hdv[j]);
      sn[j] = bf16r(mn[j] + hdv[j]);
      sd[j] = bf16r(sqrtf(v + 1e-5f));
    }
    *(short8*)(o)       = sm;
    *(short8*)(o + 128) = sx;
    *(short8*)(o + 256) = sn;
    *(short8*)(o + 384) = sd;
  }
}

// ------------------------------------------------------------------
// post_gemm v9 (unchanged from round 13/15): 128x64 tile, BK=64,
// chunk-reuse, XCD pair-affinity 1-D grid (1568 blocks),
// v_cvt_pk_bf16_f32 scale-on-stage. At the composed vmem roofline
// (~6.5 TB/s through all tiers at 98.6 us).
// ------------------------------------------------------------------
__global__ __launch_bounds__(256, 4)
void post_gemm_kernel(const short* __restrict__ A16,     // h16 in [R2c][128]
                      const short* __restrict__ aggG,    // [R2c][512] bf16
                      const short* __restrict__ Bt0, const short* __restrict__ Bt1,
                      const float* __restrict__ bias0, const float* __restrict__ bias1,
                      const float* __restrict__ amp, const float* __restrict__ att,
                      const float* __restrict__ resid,   // h fp32 (in-place with C)
                      float* __restrict__ C, short* __restrict__ C16) // h16 out
{
  __shared__ short8 As[1024];   // 16KB: [i(2)][j(2)][256] : 128 rows x 64 k
  __shared__ short8 Bs[512];    //  8KB: [i(2)][256]       :  64 cols x 64 k

  int tid = threadIdx.x;
  // XCD pair-affinity decode (grid = 1568 blocks, 1-D)
  int b = blockIdx.x;
  int pair = (b & 7) * 98 + ((b >> 3) >> 1);
  int half = (b >> 3) & 1;
  if (pair >= 782) return;              // block-uniform; before any barrier
  int row0 = pair * 128;
  int col0 = half * 64;
  int br = row0 >= M2c;
  const short* Bt = br ? Bt1 : Bt0;
  const float* bias = br ? bias1 : bias0;
  int wv = tid >> 6, ln = tid & 63;
  int lo = ln & 15, q = ln >> 4;

  int a_rq = (tid >> 6) & 3, a_q = (tid >> 4) & 3, a_lo = tid & 15;
  int b_q = (tid >> 4) & 3, b_lo = tid & 15, b_ct = (tid >> 6) & 3;

  // the two rows this thread stages (j = 0,1)
  int arow[2]; float ampv[2], attv[2];
#pragma unroll
  for (int j = 0; j < 2; j++){
    arow[j] = row0 + (a_rq + 4 * j) * 16 + a_lo;
    int lr = arow[j] - br * M2c;
    ampv[j] = amp[lr]; attv[j] = att[lr];
  }
  // the B column this thread stages
  size_t colb = (size_t)(col0 + b_ct * 16 + b_lo) * 1664;

  fx4 acc[2][4];
#pragma unroll
  for (int j = 0; j < 2; j++)
#pragma unroll
    for (int ct = 0; ct < 4; ct++) acc[j][ct] = (fx4){0.f, 0.f, 0.f, 0.f};

  short8 ra[2][2], rb[2];
  // A load: s<2 -> h16 chunk s; else agg chunk kc=(s-2)/3 (held 3 steps)
  auto loadA = [&](int s){
    if (s < 2){
#pragma unroll
      for (int i = 0; i < 2; i++){
        int k = s * 64 + i * 32 + a_q * 8;
#pragma unroll
        for (int j = 0; j < 2; j++)
          ra[i][j] = *(const short8*)(A16 + (size_t)arow[j] * 128 + k);
      }
    } else {
      int kc = (s - 2) / 3;
#pragma unroll
      for (int i = 0; i < 2; i++){
        int koff = kc * 64 + i * 32 + a_q * 8;
#pragma unroll
        for (int j = 0; j < 2; j++)
          ra[i][j] = *(const short8*)(aggG + (size_t)arow[j] * 512 + koff);
      }
    }
  };
  auto loadB = [&](int s){
    int gkb;
    if (s < 2) gkb = s * 64;
    else {
      int t = s - 2, kc = t / 3, ph = t % 3;
      gkb = (ph == 0 ? 128 : (ph == 1 ? 640 : 1152)) + kc * 64;
    }
#pragma unroll
    for (int i = 0; i < 2; i++)
      rb[i] = *(const short8*)(Bt + colb + gkb + i * 32 + b_q * 8);
  };

  loadA(0); loadB(0);
  for (int s = 0; s < 26; s++){
    int ph = (s < 2) ? 0 : (s - 2) % 3;
    __syncthreads();
    // stage A (scale-on-stage via HW packed bf16 convert; uniform per step)
    if (ph == 0){
#pragma unroll
      for (int i = 0; i < 2; i++)
#pragma unroll
        for (int j = 0; j < 2; j++) As[i * 512 + j * 256 + tid] = ra[i][j];
    } else {
#pragma unroll
      for (int i = 0; i < 2; i++)
#pragma unroll
        for (int j = 0; j < 2; j++){
          float sc = (ph == 1) ? ampv[j] : attv[j];
          short8 v = ra[i][j];
          unsigned w[4] __attribute__((aligned(16)));
#pragma unroll
          for (int e = 0; e < 4; e++){
            float f0 = bf16f(((short*)&v)[2 * e]) * sc;
            float f1 = bf16f(((short*)&v)[2 * e + 1]) * sc;
            unsigned r;
            asm("v_cvt_pk_bf16_f32 %0, %1, %2" : "=v"(r) : "v"(f0), "v"(f1));
            w[e] = r;
          }
          As[i * 512 + j * 256 + tid] = *(short8*)w;
        }
    }
#pragma unroll
    for (int i = 0; i < 2; i++) Bs[i * 256 + tid] = rb[i];
    __syncthreads();
    if (s < 25){
      loadB(s + 1);
      // next step needs a new A chunk only for: s+1 in {0,1} or ph(s+1)==0
      if (s + 1 < 2 || (s - 1) % 3 == 0) loadA(s + 1);
    }
    short8 a00 = As[wv * 64 + ln];          // k-half 0, rows wv
    short8 a10 = As[512 + wv * 64 + ln];    // k-half 1, rows wv
    short8 a01 = As[256 + wv * 64 + ln];    // k-half 0, rows wv+4
    short8 a11 = As[768 + wv * 64 + ln];    // k-half 1, rows wv+4
#pragma unroll
    for (int ct = 0; ct < 4; ct++){
      short8 b0 = Bs[ct * 64 + ln];
      short8 b1 = Bs[256 + ct * 64 + ln];
      acc[0][ct] = __builtin_amdgcn_mfma_f32_16x16x32_bf16(a00, b0, acc[0][ct], 0, 0, 0);
      acc[0][ct] = __builtin_amdgcn_mfma_f32_16x16x32_bf16(a10, b1, acc[0][ct], 0, 0, 0);
      acc[1][ct] = __builtin_amdgcn_mfma_f32_16x16x32_bf16(a01, b0, acc[1][ct], 0, 0, 0);
      acc[1][ct] = __builtin_amdgcn_mfma_f32_16x16x32_bf16(a11, b1, acc[1][ct], 0, 0, 0);
    }
  }

  // epilogue: + bias + resid (h fp32 in-place; h16 double-buffered)
#pragma unroll
  for (int j = 0; j < 2; j++){
#pragma unroll
    for (int ct = 0; ct < 4; ct++){
      int col = col0 + ct * 16 + lo;
      float bcol = bias[col];
#pragma unroll
      for (int r = 0; r < 4; r++){
        int row = row0 + (wv + 4 * j) * 16 + q * 4 + r;
        float v = acc[j][ct][r] + bcol + resid[(size_t)row * 128 + col];
        C[(size_t)row * 128 + col] = v;
        C16[(size_t)row * 128 + col] = bf16r(v);
      }
    }
  }
}

// ------------------------------------------------------------------
extern "C" void kernel_launch(void* const* d_in, const int* in_sizes, int n_in,
                              void* d_out, int out_size, void* d_ws, size_t ws_size,
                              hipStream_t stream)
{
  const int*   node_feat = (const int*)  d_in[0];
  const int*   edge_feat = (const int*)  d_in[1];
  const int*   src       = (const int*)  d_in[2];
  const int*   dst       = (const int*)  d_in[3];
  const float* aemb_f  = (const float*) d_in[5];
  const float* bemb_f  = (const float*) d_in[6];
  const float* w_pre_f = (const float*) d_in[7];
  const float* b_pre_f = (const float*) d_in[8];
  const float* w_post_f= (const float*) d_in[9];
  const float* b_post_f= (const float*) d_in[10];
  const float* w_out3  = (const float*) d_in[11];
  const float* b_out3  = (const float*) d_in[12];
  const float* aemb    = (const float*) d_in[13];
  const float* bemb    = (const float*) d_in[14];
  const float* w_pre   = (const float*) d_in[15];
  const float* b_pre   = (const float*) d_in[16];
  const float* w_post  = (const float*) d_in[17];
  const float* b_post  = (const float*) d_in[18];
  const float* w1      = (const float*) d_in[19];
  const float* b1      = (const float*) d_in[20];
  const float* w2      = (const float*) d_in[21];
  const float* b2      = (const float*) d_in[22];
  float* out = (float*)d_out;

  // ---- workspace carve (~213 MB < round-0's proven 221 MB) ----
  char* w = (char*)d_ws;
  auto carve = [&](size_t bytes) -> void* {
    void* p = (void*)w;
    w += (bytes + 255) & ~(size_t)255;
    return p;
  };
  float* h         = (float*)carve((size_t)R2c * Hc * 4);      // fp32, in-place
  short* h16_a     = (short*)carve((size_t)R2c * Hc * 2);      // double-buffered
  short* h16_b     = (short*)carve((size_t)R2c * Hc * 2);
  short* aggG      = (short*)carve((size_t)R2c * 512 * 2);     // BOTH branches
  short* btpre_all = (short*)carve((size_t)2 * Lc * 256 * 128 * 2);
  short* btpost_all= (short*)carve((size_t)2 * Lc * 128 * 1664 * 2);
  short* ezt16_all = (short*)carve((size_t)2 * Lc * 125 * Hc * 2);
  float* amp       = (float*)carve((size_t)M2c * 4);
  float* att       = (float*)carve((size_t)M2c * 4);
  int* rowstart = (int*)carve((size_t)(Nn + 1) * 4);
  int* pk_srt   = (int*)carve((size_t)Ee * 4);

  // temporaries aliased into aggG: used ONLY before the layer loop
  // (deg/cursor/part/bsums/bsum2) or ONLY after it (r3/r2). All live
  // below 16 MB -- disjoint from the pad-row regions (>= 51 MB).
  char* ali = (char*)aggG;
  float* r3     = (float*)(ali);                      // 3.07 MB
  float* r2     = (float*)(ali + (size_t)4 * 1024 * 1024);
  int*   deg    = (int*)  (ali + (size_t)8 * 1024 * 1024);
  int*   cursor = (int*)  (ali + (size_t)9 * 1024 * 1024);
  int*   part   = (int*)  (ali + (size_t)10 * 1024 * 1024);
  int*   bsums  = (int*)  (ali + (size_t)11 * 1024 * 1024);
  float* bsum2  = (float*)(ali + (size_t)12 * 1024 * 1024);

  // ---- graph preprocessing ----
  hipMemsetAsync(deg, 0, (size_t)Nn * 4, stream);
  deg_kernel<<<(Ee + 255) / 256, 256, 0, stream>>>(dst, deg, Ee);
  scan1_kernel<<<49, 1024, 0, stream>>>(deg, part, bsums, Nn);
  scan2_kernel<<<1, 64, 0, stream>>>(bsums, 49);
  scan3_kernel<<<(Nn + 255) / 256, 256, 0, stream>>>(part, bsums, rowstart, Nn);
  copy_int_kernel<<<(Nn + 255) / 256, 256, 0, stream>>>(rowstart, cursor, Nn);
  scatter_kernel<<<(Ee + 255) / 256, 256, 0, stream>>>(src, dst, edge_feat, cursor,
                                                       pk_srt, Ee);
  ampatt_kernel<<<(M2c + 255) / 256, 256, 0, stream>>>(deg, amp, att, M2c);

  // zero the aggG pad rows ONCE (fgemm_agg blocks never touch rows >= Nn)
  hipMemsetAsync(aggG + (size_t)Nn * 512, 0, (size_t)(M2c - Nn) * 512 * 2, stream);
  hipMemsetAsync(aggG + ((size_t)M2c + Nn) * 512, 0, (size_t)(M2c - Nn) * 512 * 2, stream);

  // ---- up-front shared tables ----
  bsum2_kernel<<<(2 * 125 * Hc + 255) / 256, 256, 0, stream>>>(bemb_f, bemb, bsum2);
  conv_pre_all_kernel<<<(2 * Lc * 256 * 128 + 255) / 256, 256, 0, stream>>>(
      w_pre_f, w_pre, btpre_all);
  conv_post_all_kernel<<<(2 * Lc * 1664 * 128 + 255) / 256, 256, 0, stream>>>(
      w_post_f, w_post, btpost_all);
  ezt_all_kernel<<<dim3(125, 2 * Lc), 128, 0, stream>>>(
      w_pre_f, w_pre, b_pre_f, b_pre, bsum2, ezt16_all);

  // ---- merged-branch GNN ----
  short* g_cur = h16_a;
  short* g_nxt = h16_b;
  embed2_kernel<<<(R2c * Hc + 255) / 256, 256, 0, stream>>>(
      node_feat, aemb_f, aemb, h, g_cur);

  for (int l = 0; l < Lc; l++){
    const short* pre0 = btpre_all + (size_t)(0 * Lc + l) * 256 * 128;
    const short* pre1 = btpre_all + (size_t)(1 * Lc + l) * 256 * 128;
    const short* post0 = btpost_all + (size_t)(0 * Lc + l) * 128 * 1664;
    const short* post1 = btpost_all + (size_t)(1 * Lc + l) * 128 * 1664;
    const int* ez0 = (const int*)(ezt16_all + (size_t)(0 * Lc + l) * 125 * Hc);
    const int* ez1 = (const int*)(ezt16_all + (size_t)(1 * Lc + l) * 125 * Hc);
    const float* bp0 = b_post_f + (size_t)l * 128;
    const float* bp1 = b_post   + (size_t)l * 128;

    // fused pretrans GEMM + aggregation, BOTH branches in one launch
    fgemm_agg_kernel<<<2 * Gg, 256, 0, stream>>>(
        g_cur, pre0, pre1, ez0, ez1, pk_srt, rowstart, aggG);

    // merged post GEMM: XCD pair-affinity 1-D grid (1568 blocks)
    post_gemm_kernel<<<1568, 256, 0, stream>>>(
        g_cur, aggG, post0, post1, bp0, bp1, amp, att, h, h, g_nxt);

    { short* t = g_cur; g_cur = g_nxt; g_nxt = t; }
  }

  readout2_kernel<<<2 * Gg, 128, 0, stream>>>(h, r3, r2);
  head_kernel<<<Gg, 256, 0, stream>>>(r2, r3, w_out3, b_out3, w1, b1, w2, b2, out);
}

// Round 17
// 1173.623 us; speedup vs baseline: 1.0072x; 1.0072x over previous
//
#include <hip/hip_runtime.h>
#include <hip/hip_bf16.h>
#include <math.h>

// Problem constants (fixed by the reference)
#define Nn 50000
#define Ee 400000
#define Gg 2000
#define NPGc 25
#define Hc 128
#define Lc 5
// branch row padding: 128-aligned so every GEMM tile is branch-homogeneous
#define M2c 50048              // = 64 * 782 = 128 * 391
#define R2c 100096             // = 2 * M2c

typedef __attribute__((ext_vector_type(8))) short short8;   // 8 bf16 = 4 VGPRs
typedef __attribute__((ext_vector_type(4))) float fx4;      // MFMA accumulator

__device__ inline short bf16r(float x){
  unsigned u = __float_as_uint(x);
  unsigned r = (u + 0x7fffu + ((u >> 16) & 1u)) >> 16;
  return (short)r;
}
__device__ inline float bf16f(short s){
  return __uint_as_float(((unsigned)(unsigned short)s) << 16);
}

// ------------------------------------------------------------------
// Graph preprocessing
// ------------------------------------------------------------------
__global__ void deg_kernel(const int* __restrict__ dst, int* __restrict__ deg, int E){
  int i = blockIdx.x * blockDim.x + threadIdx.x;
  if (i < E) atomicAdd(&deg[dst[i]], 1);
}

__global__ void scan1_kernel(const int* __restrict__ deg, int* __restrict__ part,
                             int* __restrict__ bsums, int n){
  __shared__ int tmp[1024];
  int b = blockIdx.x, t = threadIdx.x;
  int i = b * 1024 + t;
  int v = (i < n) ? deg[i] : 0;
  tmp[t] = v;
  __syncthreads();
  for (int off = 1; off < 1024; off <<= 1){
    int add = (t >= off) ? tmp[t - off] : 0;
    __syncthreads();
    tmp[t] += add;
    __syncthreads();
  }
  part[i] = tmp[t];
  if (t == 1023) bsums[b] = tmp[1023];
}
__global__ void scan2_kernel(int* __restrict__ bsums, int nb){
  if (threadIdx.x == 0){
    int s = 0;
    for (int i = 0; i < nb; i++){ s += bsums[i]; bsums[i] = s; }
  }
}
__global__ void scan3_kernel(const int* __restrict__ part, const int* __restrict__ bsums,
                             int* __restrict__ rowstart, int n){
  int i = blockIdx.x * blockDim.x + threadIdx.x;
  if (i == 0) rowstart[0] = 0;
  if (i < n){
    int b = i >> 10;
    int base = b ? bsums[b - 1] : 0;
    rowstart[i + 1] = part[i] + base;
  }
}

__global__ void copy_int_kernel(const int* __restrict__ a, int* __restrict__ b, int n){
  int i = blockIdx.x * blockDim.x + threadIdx.x;
  if (i < n) b[i] = a[i];
}

// packed edge record: (code << 16) | (src % NPGc)  -- src and dst are
// ALWAYS in the same graph (reference construction), so the graph-local
// src index (0..24) is sufficient.
__global__ void scatter_kernel(const int* __restrict__ src, const int* __restrict__ dst,
                               const int* __restrict__ ef, int* cursor,
                               int* __restrict__ pk_srt, int E){
  int i = blockIdx.x * blockDim.x + threadIdx.x;
  if (i >= E) return;
  int p = atomicAdd(&cursor[dst[i]], 1);
  int code = ef[i * 3 + 0] * 25 + ef[i * 3 + 1] * 5 + ef[i * 3 + 2];
  pk_srt[p] = (code << 16) | (src[i] % NPGc);
}

// amp/att sized M2c (branch-local rows; both branches share the graph)
__global__ void ampatt_kernel(const int* __restrict__ deg, float* __restrict__ amp,
                              float* __restrict__ att, int n){
  int i = blockIdx.x * blockDim.x + threadIdx.x;
  if (i >= n) return;
  if (i >= Nn){ amp[i] = 0.f; att[i] = 0.f; return; }
  float d = (float)deg[i];
  float ld = logf(d + 1.0f);
  amp[i] = ld;
  att[i] = (deg[i] > 0) ? (1.0f / ld) : 0.0f;
}

// ------------------------------------------------------------------
// Node embedding, BOTH branches stacked
// ------------------------------------------------------------------
__global__ void embed2_kernel(const int* __restrict__ nf,
                              const float* __restrict__ aemb_f,
                              const float* __restrict__ aemb_t,
                              float* __restrict__ h, short* __restrict__ h16){
  int idx = blockIdx.x * blockDim.x + threadIdx.x;
  if (idx >= R2c * Hc) return;
  int n = idx >> 7, c = idx & 127;
  int br = n >= M2c;
  int local = n - br * M2c;
  if (local >= Nn){ h[idx] = 0.f; h16[idx] = 0; return; }
  const float* aemb = br ? aemb_t : aemb_f;
  float s = 0.f;
#pragma unroll
  for (int f = 0; f < 9; f++){
    int row = nf[local * 9 + f] + 16 * f;
    s += aemb[row * Hc + c];
  }
  h[idx] = s;
  h16[idx] = bf16r(s);
}

// bsum2[b][code][c]: 125 distinct edge embeddings, both branches
__global__ void bsum2_kernel(const float* __restrict__ bemb_f, const float* __restrict__ bemb_t,
                             float* __restrict__ bsum2){
  int idx = blockIdx.x * blockDim.x + threadIdx.x;
  if (idx >= 2 * 125 * Hc) return;
  int b = idx / (125 * Hc);
  int rem = idx % (125 * Hc);
  int code = rem >> 7, c = rem & 127;
  int e0 = code / 25, e1 = (code / 5) % 5, e2 = code % 5;
  const float* bemb = b ? bemb_t : bemb_f;
  bsum2[idx] = bemb[e0 * Hc + c] + bemb[(5 + e1) * Hc + c] + bemb[(10 + e2) * Hc + c];
}

// ------------------------------------------------------------------
// up-front weight converts, both branches x 5 layers
// ------------------------------------------------------------------
__global__ void conv_pre_all_kernel(const float* __restrict__ wpre_f,
                                    const float* __restrict__ wpre_t,
                                    short* __restrict__ btpre_all){
  int idx = blockIdx.x * blockDim.x + threadIdx.x;
  if (idx >= 2 * Lc * 256 * 128) return;
  int bl = idx / (256 * 128);
  int rem = idx % (256 * 128);
  int col = rem >> 7, k = rem & 127;
  int b = bl / Lc, l = bl % Lc;
  const float* wl = (b ? wpre_t : wpre_f) + (size_t)l * 384 * 128;
  float v = (col < 128) ? wl[k * 128 + col] : wl[(128 + k) * 128 + (col - 128)];
  btpre_all[(size_t)bl * 256 * 128 + col * 128 + k] = bf16r(v);
}
__global__ void conv_post_all_kernel(const float* __restrict__ wpost_f,
                                     const float* __restrict__ wpost_t,
                                     short* __restrict__ btpost_all){
  int idx = blockIdx.x * blockDim.x + threadIdx.x;
  if (idx >= 2 * Lc * 1664 * 128) return;
  int bl = idx / (1664 * 128);
  int rem = idx % (1664 * 128);
  int k = rem >> 7, c = rem & 127;
  int b = bl / Lc, l = bl % Lc;
  const float* wl = (b ? wpost_t : wpost_f) + (size_t)l * 1664 * 128;
  btpost_all[(size_t)bl * 128 * 1664 + (size_t)c * 1664 + k] = bf16r(wl[(size_t)k * 128 + c]);
}

// ezt16_all[bl][code][c] (bf16) = bsum2[b][code][:] @ W_e[b,l] + b_pre[b,l]
__global__ void ezt_all_kernel(const float* __restrict__ wpre_f, const float* __restrict__ wpre_t,
                               const float* __restrict__ bpre_f, const float* __restrict__ bpre_t,
                               const float* __restrict__ bsum2, short* __restrict__ ezt16_all){
  int code = blockIdx.x;
  int bl   = blockIdx.y;
  int t = threadIdx.x;
  int b = bl / Lc, l = bl % Lc;
  const float* wl = (b ? wpre_t : wpre_f) + (size_t)l * 384 * 128 + 256 * 128;
  const float* bp = (b ? bpre_t : bpre_f) + (size_t)l * 128;
  __shared__ float bs[128];
  bs[t] = bsum2[((size_t)b * 125 + code) * 128 + t];
  __syncthreads();
  float acc = bp[t];
#pragma unroll 8
  for (int k = 0; k < 128; k++) acc += bs[k] * wl[k * 128 + t];
  ezt16_all[((size_t)bl * 125 + code) * 128 + t] = bf16r(acc);
}

// ------------------------------------------------------------------
// Graph readout (merged): block b*Gg+g -> branch b, graph g
// ------------------------------------------------------------------
__global__ void readout2_kernel(const float* __restrict__ h,
                                float* __restrict__ r3, float* __restrict__ r2){
  int bi = blockIdx.x;
  int br = bi >= Gg;
  int g = bi - br * Gg;
  int c = threadIdx.x;
  float mn = 3.402823466e38f, mx = -3.402823466e38f, s = 0.f;
  const float* hp = h + ((size_t)br * M2c + (size_t)g * NPGc) * Hc + c;
#pragma unroll
  for (int i = 0; i < NPGc; i++){
    float v = hp[i * Hc];
    mn = fminf(mn, v); mx = fmaxf(mx, v); s += v;
  }
  float* r = br ? r2 : r3;
  r[(size_t)g * 384 + c]       = mn;
  r[(size_t)g * 384 + 128 + c] = mx;
  r[(size_t)g * 384 + 256 + c] = s * (1.0f / NPGc);
}

// ------------------------------------------------------------------
// Fused head, one graph per block
// ------------------------------------------------------------------
__global__ __launch_bounds__(256)
void head_kernel(const float* __restrict__ r2, const float* __restrict__ r3,
                 const float* __restrict__ w_out3, const float* __restrict__ b_out3,
                 const float* __restrict__ w1, const float* __restrict__ b1,
                 const float* __restrict__ w2, const float* __restrict__ b2,
                 float* __restrict__ out)
{
  __shared__ float r3_s[384];
  __shared__ float x_s[640];
  __shared__ float h1_s[128];
  __shared__ float partial[256];
  int g = blockIdx.x, t = threadIdx.x;

  for (int i = t; i < 384; i += 256){
    float v2 = r2[(size_t)g * 384 + i];
    r3_s[i] = r3[(size_t)g * 384 + i];
    x_s[i] = v2;
  }
  __syncthreads();

  {
    float acc = b_out3[t];
#pragma unroll 8
    for (int k = 0; k < 384; k++) acc += r3_s[k] * w_out3[k * 256 + t];
    x_s[384 + t] = acc;
  }
  __syncthreads();

  {
    int c = t & 127, half = t >> 7;
    float acc = half ? 0.f : b1[c];
    int kb = half * 320;
#pragma unroll 8
    for (int k = kb; k < kb + 320; k++) acc += x_s[k] * w1[k * 128 + c];
    partial[t] = acc;
  }
  __syncthreads();
  if (t < 128) h1_s[t] = fmaxf(partial[t] + partial[t + 128], 0.f);
  __syncthreads();

  {
    int c = t & 127, half = t >> 7;
    float acc = half ? 0.f : b2[c];
    int kb = half * 64;
#pragma unroll 8
    for (int k = kb; k < kb + 64; k++) acc += h1_s[k] * w2[k * 128 + c];
    partial[t] = acc;
  }
  __syncthreads();
  if (t < 128) out[(size_t)g * 128 + t] = partial[t] + partial[t + 128];
}

// ------------------------------------------------------------------
// fgemm_agg v5 (round-15 best, 5 blocks/CU): FUSED pretrans GEMM +
// aggregation with hd-factoring. VALU-issue-bound at this form;
// occupancy 5->6 measured slightly negative, so locked at 5.
// ------------------------------------------------------------------
__global__ __launch_bounds__(256, 5)
void fgemm_agg_kernel(const short* __restrict__ h16,     // [R2c][128]
                      const short* __restrict__ pre0, const short* __restrict__ pre1,
                      const int* __restrict__ ez0, const int* __restrict__ ez1,
                      const int* __restrict__ pk_srt, const int* __restrict__ rowstart,
                      short* __restrict__ aggG)          // [R2c][512]
{
  __shared__ short h_s[32 * 128];     // 8 KB (rows 25..31 unstaged garbage)
  __shared__ short hsd_s[32 * 256];   // 16 KB
  __shared__ int pk_s[512];           // 2 KB graph edge list

  int tid = threadIdx.x;
  int bi = blockIdx.x;
  int brn = bi >= Gg;
  int g = bi - brn * Gg;
  const short* h16b = h16 + (size_t)brn * M2c * 128;
  const short* Bt = brn ? pre1 : pre0;
  const int* ez16 = brn ? ez1 : ez0;
  short* aggOut = aggG + (size_t)brn * M2c * 512;
  int base = g * NPGc;

  // ---- Phase A: stage h (swizzled) + the graph's edge list ----
  int e_lo = rowstart[base];
  {
    int ecnt = rowstart[base + NPGc] - e_lo;
    if (ecnt > 512) ecnt = 512;
    for (int t = tid; t < ecnt; t += 256) pk_s[t] = pk_srt[e_lo + t];

    const int* src = (const int*)(h16b + (size_t)base * 128);
    int* dst = (int*)h_s;
    for (int t = tid; t < NPGc * 64; t += 256){
      int row = t >> 6, ci = t & 63;
      dst[row * 64 + (ci ^ ((row & 7) << 2))] = src[t];
    }
  }
  __syncthreads();

  // ---- Phase B: MFMA GEMM 32x256 = 32x128 @ 128x256 ----
  int wv = tid >> 6, ln = tid & 63;
  int l15 = ln & 15, lq = ln >> 4;
  {
    fx4 acc[2][4];
#pragma unroll
    for (int mt = 0; mt < 2; mt++)
#pragma unroll
      for (int ct = 0; ct < 4; ct++) acc[mt][ct] = (fx4){0.f, 0.f, 0.f, 0.f};

    // A fragments from LDS: lane l -> row = mt*16 + (l&15), k = ks*32 + (l>>4)*8
    short8 af[2][4];
#pragma unroll
    for (int mt = 0; mt < 2; mt++){
      int row = mt * 16 + l15;
#pragma unroll
      for (int ks = 0; ks < 4; ks++){
        int sk = ks * 32 + lq * 8;
        af[mt][ks] = *(const short8*)(h_s + row * 128 + (sk ^ ((row & 7) << 3)));
      }
    }
    // B fragments from global: col = wv*64 + ct*16 + (l&15), same k mapping
#pragma unroll
    for (int ks = 0; ks < 4; ks++){
#pragma unroll
      for (int ct = 0; ct < 4; ct++){
        int col = wv * 64 + ct * 16 + l15;
        short8 bf = *(const short8*)(Bt + (size_t)col * 128 + ks * 32 + lq * 8);
        acc[0][ct] = __builtin_amdgcn_mfma_f32_16x16x32_bf16(af[0][ks], bf, acc[0][ct], 0, 0, 0);
        acc[1][ct] = __builtin_amdgcn_mfma_f32_16x16x32_bf16(af[1][ks], bf, acc[1][ct], 0, 0, 0);
      }
    }
    // write hsd to LDS (C/D: col = lane&15, row = (lane>>4)*4 + r)
#pragma unroll
    for (int mt = 0; mt < 2; mt++){
#pragma unroll
      for (int ct = 0; ct < 4; ct++){
        int cc = wv * 64 + ct * 16 + l15;
#pragma unroll
        for (int r = 0; r < 4; r++){
          int row = mt * 16 + lq * 4 + r;
          hsd_s[row * 256 + (cc ^ ((row & 7) << 3))] = bf16r(acc[mt][ct][r]);
        }
      }
    }
  }
  __syncthreads();

  // ---- Phase C: aggregation (pk + hs from LDS; hd factored out) ----
  int sub = tid & 15;
  int go = sub * 4;
  const int* hsd_i = (const int*)hsd_s;

#pragma unroll
  for (int rnd = 0; rnd < 2; rnd++){
    int nd = rnd * 16 + (tid >> 4);
    if (nd >= NPGc) continue;
    int node = base + nd;
    int e0 = rowstart[node], e1 = rowstart[node + 1];
    short* o = aggOut + (size_t)node * 512 + sub * 8;
    if (e1 <= e0){
      short8 z = {0, 0, 0, 0, 0, 0, 0, 0};
      *(short8*)(o)       = z;
      *(short8*)(o + 128) = z;
      *(short8*)(o + 256) = z;
      *(short8*)(o + 384) = z;
      continue;
    }

    // dst-half of pretrans (LDS, swizzled): ints 64+go of row nd
    float hdv[8];
    {
      int4 hd = *(const int4*)(hsd_i + nd * 128 + ((64 + go) ^ ((nd & 7) << 2)));
      const int* hp = (const int*)&hd;
#pragma unroll
      for (int i = 0; i < 4; i++){
        hdv[2 * i]     = __uint_as_float(((unsigned)hp[i]) << 16);
        hdv[2 * i + 1] = __uint_as_float(((unsigned)hp[i]) & 0xffff0000u);
      }
    }

    float sum[8], sq[8], mx[8], mn[8];
#pragma unroll
    for (int j = 0; j < 8; j++){
      sum[j] = 0.f; sq[j] = 0.f;
      mx[j] = -3.402823466e38f; mn[j] = 3.402823466e38f;
    }

    for (int k = e0; k < e1; k += 4){
      int pk[4];
#pragma unroll
      for (int t2 = 0; t2 < 4; t2++){
        int kk = (k + t2 < e1) ? (k + t2) : (e1 - 1);
        int rel = kk - e_lo;
        pk[t2] = (rel < 512) ? pk_s[rel] : pk_srt[kk];
      }
      int4 ev[4], hv[4];
#pragma unroll
      for (int t2 = 0; t2 < 4; t2++){
        int s = pk[t2] & 0xffff;
        ev[t2] = *(const int4*)(ez16 + (pk[t2] >> 16) * 64 + go);
        hv[t2] = *(const int4*)(hsd_i + s * 128 + (go ^ ((s & 7) << 2)));
      }
#pragma unroll
      for (int t2 = 0; t2 < 4; t2++){
        if (k + t2 < e1){
          const int* pp = (const int*)&hv[t2];
          const int* ee = (const int*)&ev[t2];
#pragma unroll
          for (int i = 0; i < 4; i++){
            float y0 = __uint_as_float(((unsigned)pp[i]) << 16)
                     + __uint_as_float(((unsigned)ee[i]) << 16);
            float y1 = __uint_as_float(((unsigned)pp[i]) & 0xffff0000u)
                     + __uint_as_float(((unsigned)ee[i]) & 0xffff0000u);
            sum[2 * i] += y0;     sq[2 * i] += y0 * y0;
            mx[2 * i] = fmaxf(mx[2 * i], y0); mn[2 * i] = fminf(mn[2 * i], y0);
            sum[2 * i + 1] += y1; sq[2 * i + 1] += y1 * y1;
            mx[2 * i + 1] = fmaxf(mx[2 * i + 1], y1); mn[2 * i + 1] = fminf(mn[2 * i + 1], y1);
          }
        }
      }
    }

    float d = (float)(e1 - e0);
    float rd = 1.0f / d;
    short8 sm, sx, sn, sd;
#pragma unroll
    for (int j = 0; j < 8; j++){
      float my = sum[j] * rd;
      float v = sq[j] * rd - my * my; v = v > 0.f ? v : 0.f;  // var shift-invariant
      sm[j] = bf16r(my + hdv[j]);
      sx[j] = bf16r(mx[j] + hdv[j]);
      sn[j] = bf16r(mn[j] + hdv[j]);
      sd[j] = bf16r(sqrtf(v + 1e-5f));
    }
    *(short8*)(o)       = sm;
    *(short8*)(o + 128) = sx;
    *(short8*)(o + 256) = sn;
    *(short8*)(o + 384) = sd;
  }
}

// ------------------------------------------------------------------
// post_gemm v9 (round-13/15 best): 128x64 tile, BK=64, chunk-reuse,
// XCD pair-affinity 1-D grid (1568 blocks), v_cvt_pk_bf16_f32
// scale-on-stage. At the composed vmem roofline (~6.5 TB/s through
// all tiers at 98.6 us).
// ------------------------------------------------------------------
__global__ __launch_bounds__(256, 4)
void post_gemm_kernel(const short* __restrict__ A16,     // h16 in [R2c][128]
                      const short* __restrict__ aggG,    // [R2c][512] bf16
                      const short* __restrict__ Bt0, const short* __restrict__ Bt1,
                      const float* __restrict__ bias0, const float* __restrict__ bias1,
                      const float* __restrict__ amp, const float* __restrict__ att,
                      const float* __restrict__ resid,   // h fp32 (in-place with C)
                      float* __restrict__ C, short* __restrict__ C16) // h16 out
{
  __shared__ short8 As[1024];   // 16KB: [i(2)][j(2)][256] : 128 rows x 64 k
  __shared__ short8 Bs[512];    //  8KB: [i(2)][256]       :  64 cols x 64 k

  int tid = threadIdx.x;
  // XCD pair-affinity decode (grid = 1568 blocks, 1-D)
  int b = blockIdx.x;
  int pair = (b & 7) * 98 + ((b >> 3) >> 1);
  int half = (b >> 3) & 1;
  if (pair >= 782) return;              // block-uniform; before any barrier
  int row0 = pair * 128;
  int col0 = half * 64;
  int br = row0 >= M2c;
  const short* Bt = br ? Bt1 : Bt0;
  const float* bias = br ? bias1 : bias0;
  int wv = tid >> 6, ln = tid & 63;
  int lo = ln & 15, q = ln >> 4;

  int a_rq = (tid >> 6) & 3, a_q = (tid >> 4) & 3, a_lo = tid & 15;
  int b_q = (tid >> 4) & 3, b_lo = tid & 15, b_ct = (tid >> 6) & 3;

  // the two rows this thread stages (j = 0,1)
  int arow[2]; float ampv[2], attv[2];
#pragma unroll
  for (int j = 0; j < 2; j++){
    arow[j] = row0 + (a_rq + 4 * j) * 16 + a_lo;
    int lr = arow[j] - br * M2c;
    ampv[j] = amp[lr]; attv[j] = att[lr];
  }
  // the B column this thread stages
  size_t colb = (size_t)(col0 + b_ct * 16 + b_lo) * 1664;

  fx4 acc[2][4];
#pragma unroll
  for (int j = 0; j < 2; j++)
#pragma unroll
    for (int ct = 0; ct < 4; ct++) acc[j][ct] = (fx4){0.f, 0.f, 0.f, 0.f};

  short8 ra[2][2], rb[2];
  // A load: s<2 -> h16 chunk s; else agg chunk kc=(s-2)/3 (held 3 steps)
  auto loadA = [&](int s){
    if (s < 2){
#pragma unroll
      for (int i = 0; i < 2; i++){
        int k = s * 64 + i * 32 + a_q * 8;
#pragma unroll
        for (int j = 0; j < 2; j++)
          ra[i][j] = *(const short8*)(A16 + (size_t)arow[j] * 128 + k);
      }
    } else {
      int kc = (s - 2) / 3;
#pragma unroll
      for (int i = 0; i < 2; i++){
        int koff = kc * 64 + i * 32 + a_q * 8;
#pragma unroll
        for (int j = 0; j < 2; j++)
          ra[i][j] = *(const short8*)(aggG + (size_t)arow[j] * 512 + koff);
      }
    }
  };
  auto loadB = [&](int s){
    int gkb;
    if (s < 2) gkb = s * 64;
    else {
      int t = s - 2, kc = t / 3, ph = t % 3;
      gkb = (ph == 0 ? 128 : (ph == 1 ? 640 : 1152)) + kc * 64;
    }
#pragma unroll
    for (int i = 0; i < 2; i++)
      rb[i] = *(const short8*)(Bt + colb + gkb + i * 32 + b_q * 8);
  };

  loadA(0); loadB(0);
  for (int s = 0; s < 26; s++){
    int ph = (s < 2) ? 0 : (s - 2) % 3;
    __syncthreads();
    // stage A (scale-on-stage via HW packed bf16 convert; uniform per step)
    if (ph == 0){
#pragma unroll
      for (int i = 0; i < 2; i++)
#pragma unroll
        for (int j = 0; j < 2; j++) As[i * 512 + j * 256 + tid] = ra[i][j];
    } else {
#pragma unroll
      for (int i = 0; i < 2; i++)
#pragma unroll
        for (int j = 0; j < 2; j++){
          float sc = (ph == 1) ? ampv[j] : attv[j];
          short8 v = ra[i][j];
          unsigned w[4] __attribute__((aligned(16)));
#pragma unroll
          for (int e = 0; e < 4; e++){
            float f0 = bf16f(((short*)&v)[2 * e]) * sc;
            float f1 = bf16f(((short*)&v)[2 * e + 1]) * sc;
            unsigned r;
            asm("v_cvt_pk_bf16_f32 %0, %1, %2" : "=v"(r) : "v"(f0), "v"(f1));
            w[e] = r;
          }
          As[i * 512 + j * 256 + tid] = *(short8*)w;
        }
    }
#pragma unroll
    for (int i = 0; i < 2; i++) Bs[i * 256 + tid] = rb[i];
    __syncthreads();
    if (s < 25){
      loadB(s + 1);
      // next step needs a new A chunk only for: s+1 in {0,1} or ph(s+1)==0
      if (s + 1 < 2 || (s - 1) % 3 == 0) loadA(s + 1);
    }
    short8 a00 = As[wv * 64 + ln];          // k-half 0, rows wv
    short8 a10 = As[512 + wv * 64 + ln];    // k-half 1, rows wv
    short8 a01 = As[256 + wv * 64 + ln];    // k-half 0, rows wv+4
    short8 a11 = As[768 + wv * 64 + ln];    // k-half 1, rows wv+4
#pragma unroll
    for (int ct = 0; ct < 4; ct++){
      short8 b0 = Bs[ct * 64 + ln];
      short8 b1 = Bs[256 + ct * 64 + ln];
      acc[0][ct] = __builtin_amdgcn_mfma_f32_16x16x32_bf16(a00, b0, acc[0][ct], 0, 0, 0);
      acc[0][ct] = __builtin_amdgcn_mfma_f32_16x16x32_bf16(a10, b1, acc[0][ct], 0, 0, 0);
      acc[1][ct] = __builtin_amdgcn_mfma_f32_16x16x32_bf16(a01, b0, acc[1][ct], 0, 0, 0);
      acc[1][ct] = __builtin_amdgcn_mfma_f32_16x16x32_bf16(a11, b1, acc[1][ct], 0, 0, 0);
    }
  }

  // epilogue: + bias + resid (h fp32 in-place; h16 double-buffered)
#pragma unroll
  for (int j = 0; j < 2; j++){
#pragma unroll
    for (int ct = 0; ct < 4; ct++){
      int col = col0 + ct * 16 + lo;
      float bcol = bias[col];
#pragma unroll
      for (int r = 0; r < 4; r++){
        int row = row0 + (wv + 4 * j) * 16 + q * 4 + r;
        float v = acc[j][ct][r] + bcol + resid[(size_t)row * 128 + col];
        C[(size_t)row * 128 + col] = v;
        C16[(size_t)row * 128 + col] = bf16r(v);
      }
    }
  }
}

// ------------------------------------------------------------------
extern "C" void kernel_launch(void* const* d_in, const int* in_sizes, int n_in,
                              void* d_out, int out_size, void* d_ws, size_t ws_size,
                              hipStream_t stream)
{
  const int*   node_feat = (const int*)  d_in[0];
  const int*   edge_feat = (const int*)  d_in[1];
  const int*   src       = (const int*)  d_in[2];
  const int*   dst       = (const int*)  d_in[3];
  const float* aemb_f  = (const float*) d_in[5];
  const float* bemb_f  = (const float*) d_in[6];
  const float* w_pre_f = (const float*) d_in[7];
  const float* b_pre_f = (const float*) d_in[8];
  const float* w_post_f= (const float*) d_in[9];
  const float* b_post_f= (const float*) d_in[10];
  const float* w_out3  = (const float*) d_in[11];
  const float* b_out3  = (const float*) d_in[12];
  const float* aemb    = (const float*) d_in[13];
  const float* bemb    = (const float*) d_in[14];
  const float* w_pre   = (const float*) d_in[15];
  const float* b_pre   = (const float*) d_in[16];
  const float* w_post  = (const float*) d_in[17];
  const float* b_post  = (const float*) d_in[18];
  const float* w1      = (const float*) d_in[19];
  const float* b1      = (const float*) d_in[20];
  const float* w2      = (const float*) d_in[21];
  const float* b2      = (const float*) d_in[22];
  float* out = (float*)d_out;

  // ---- workspace carve (~213 MB < round-0's proven 221 MB) ----
  char* w = (char*)d_ws;
  auto carve = [&](size_t bytes) -> void* {
    void* p = (void*)w;
    w += (bytes + 255) & ~(size_t)255;
    return p;
  };
  float* h         = (float*)carve((size_t)R2c * Hc * 4);      // fp32, in-place
  short* h16_a     = (short*)carve((size_t)R2c * Hc * 2);      // double-buffered
  short* h16_b     = (short*)carve((size_t)R2c * Hc * 2);
  short* aggG      = (short*)carve((size_t)R2c * 512 * 2);     // BOTH branches
  short* btpre_all = (short*)carve((size_t)2 * Lc * 256 * 128 * 2);
  short* btpost_all= (short*)carve((size_t)2 * Lc * 128 * 1664 * 2);
  short* ezt16_all = (short*)carve((size_t)2 * Lc * 125 * Hc * 2);
  float* amp       = (float*)carve((size_t)M2c * 4);
  float* att       = (float*)carve((size_t)M2c * 4);
  int* rowstart = (int*)carve((size_t)(Nn + 1) * 4);
  int* pk_srt   = (int*)carve((size_t)Ee * 4);

  // temporaries aliased into aggG: used ONLY before the layer loop
  // (deg/cursor/part/bsums/bsum2) or ONLY after it (r3/r2). All live
  // below 16 MB -- disjoint from the pad-row regions (>= 51 MB).
  char* ali = (char*)aggG;
  float* r3     = (float*)(ali);                      // 3.07 MB
  float* r2     = (float*)(ali + (size_t)4 * 1024 * 1024);
  int*   deg    = (int*)  (ali + (size_t)8 * 1024 * 1024);
  int*   cursor = (int*)  (ali + (size_t)9 * 1024 * 1024);
  int*   part   = (int*)  (ali + (size_t)10 * 1024 * 1024);
  int*   bsums  = (int*)  (ali + (size_t)11 * 1024 * 1024);
  float* bsum2  = (float*)(ali + (size_t)12 * 1024 * 1024);

  // ---- graph preprocessing ----
  hipMemsetAsync(deg, 0, (size_t)Nn * 4, stream);
  deg_kernel<<<(Ee + 255) / 256, 256, 0, stream>>>(dst, deg, Ee);
  scan1_kernel<<<49, 1024, 0, stream>>>(deg, part, bsums, Nn);
  scan2_kernel<<<1, 64, 0, stream>>>(bsums, 49);
  scan3_kernel<<<(Nn + 255) / 256, 256, 0, stream>>>(part, bsums, rowstart, Nn);
  copy_int_kernel<<<(Nn + 255) / 256, 256, 0, stream>>>(rowstart, cursor, Nn);
  scatter_kernel<<<(Ee + 255) / 256, 256, 0, stream>>>(src, dst, edge_feat, cursor,
                                                       pk_srt, Ee);
  ampatt_kernel<<<(M2c + 255) / 256, 256, 0, stream>>>(deg, amp, att, M2c);

  // zero the aggG pad rows ONCE (fgemm_agg blocks never touch rows >= Nn)
  hipMemsetAsync(aggG + (size_t)Nn * 512, 0, (size_t)(M2c - Nn) * 512 * 2, stream);
  hipMemsetAsync(aggG + ((size_t)M2c + Nn) * 512, 0, (size_t)(M2c - Nn) * 512 * 2, stream);

  // ---- up-front shared tables ----
  bsum2_kernel<<<(2 * 125 * Hc + 255) / 256, 256, 0, stream>>>(bemb_f, bemb, bsum2);
  conv_pre_all_kernel<<<(2 * Lc * 256 * 128 + 255) / 256, 256, 0, stream>>>(
      w_pre_f, w_pre, btpre_all);
  conv_post_all_kernel<<<(2 * Lc * 1664 * 128 + 255) / 256, 256, 0, stream>>>(
      w_post_f, w_post, btpost_all);
  ezt_all_kernel<<<dim3(125, 2 * Lc), 128, 0, stream>>>(
      w_pre_f, w_pre, b_pre_f, b_pre, bsum2, ezt16_all);

  // ---- merged-branch GNN ----
  short* g_cur = h16_a;
  short* g_nxt = h16_b;
  embed2_kernel<<<(R2c * Hc + 255) / 256, 256, 0, stream>>>(
      node_feat, aemb_f, aemb, h, g_cur);

  for (int l = 0; l < Lc; l++){
    const short* pre0 = btpre_all + (size_t)(0 * Lc + l) * 256 * 128;
    const short* pre1 = btpre_all + (size_t)(1 * Lc + l) * 256 * 128;
    const short* post0 = btpost_all + (size_t)(0 * Lc + l) * 128 * 1664;
    const short* post1 = btpost_all + (size_t)(1 * Lc + l) * 128 * 1664;
    const int* ez0 = (const int*)(ezt16_all + (size_t)(0 * Lc + l) * 125 * Hc);
    const int* ez1 = (const int*)(ezt16_all + (size_t)(1 * Lc + l) * 125 * Hc);
    const float* bp0 = b_post_f + (size_t)l * 128;
    const float* bp1 = b_post   + (size_t)l * 128;

    // fused pretrans GEMM + aggregation, BOTH branches in one launch
    fgemm_agg_kernel<<<2 * Gg, 256, 0, stream>>>(
        g_cur, pre0, pre1, ez0, ez1, pk_srt, rowstart, aggG);

    // merged post GEMM: XCD pair-affinity 1-D grid (1568 blocks)
    post_gemm_kernel<<<1568, 256, 0, stream>>>(
        g_cur, aggG, post0, post1, bp0, bp1, amp, att, h, h, g_nxt);

    { short* t = g_cur; g_cur = g_nxt; g_nxt = t; }
  }

  readout2_kernel<<<2 * Gg, 128, 0, stream>>>(h, r3, r2);
  head_kernel<<<Gg, 256, 0, stream>>>(r2, r3, w_out3, b_out3, w1, b1, w2, b2, out);
}